// Round 8
// baseline (317.311 us; speedup 1.0000x reference)
//
#include <hip/hip_runtime.h>
#include <math.h>

#define BATCH 64
#define NPG 9
#define N_NODES 576
#define HD 128
#define SPEC_LEN 1801
#define S1DIM 900
#define SCOMP 100
#define ASL 243
#define NT 15          // n-tiles of 64 over 900
#define KC 33          // K chunks for GEMM1
#define KCH 55         // 33*55 = 1815 >= 1801
#define KPAD 56        // padded chunk; k >= klen zeroed in BOTH operands
#define G1BLK (NT * KC)            // 495
#define GRID_BLKS (G1BLK + 144)    // 639

// Device-scope grid barrier: counter in workspace (zeroed via hipMemsetAsync
// before launch). Release: __threadfence() (L2 writeback to LLC) + atomicAdd.
// Spin: device-scope atomic read. Acquire: __threadfence() (L2 invalidate).
// Safe only because all GRID_BLKS blocks are co-resident (LDS 29.6KB -> 5
// blocks/CU; __launch_bounds__(256,3) -> >=3 blocks/CU -> 768 >= 639).
__device__ __forceinline__ void grid_barrier(unsigned* cnt, unsigned target) {
    __syncthreads();                       // drains this block's vmem (implicit waitcnt)
    if (threadIdx.x == 0) {
        __threadfence();                   // release: push this XCD's L2 to LLC
        atomicAdd(cnt, 1u);
        while (atomicAdd(cnt, 0u) < target) { __builtin_amdgcn_s_sleep(8); }
    }
    __syncthreads();
    __threadfence();                       // acquire: invalidate stale L2 lines
}

__global__ __launch_bounds__(256, 3) void kfused(
        const float* __restrict__ specs, const float* __restrict__ W1,
        const float* __restrict__ nf, const float* __restrict__ Wa2,
        const float* __restrict__ b1, const float* __restrict__ W2,
        const float* __restrict__ b2,
        const float* __restrict__ Wv1, const float* __restrict__ bv1,
        const float* __restrict__ Wv2, const float* __restrict__ bv2,
        const float* __restrict__ ba2, const float* __restrict__ Wf,
        const float* __restrict__ bfb,
        const int* __restrict__ indexmask, const float* __restrict__ mask,
        float* __restrict__ P, float* __restrict__ Pc, float* __restrict__ AB,
        unsigned* __restrict__ bar,
        float* __restrict__ out, float* __restrict__ vout) {
    int bb = blockIdx.x, tid = threadIdx.x;

    __shared__ union {
        struct { float sA[KPAD * 68]; float sB[KPAD * 64]; } g1;   // 29568 B
        struct { float snf[4 * HD]; } ab;
        struct { float sld[100]; } g2;
        struct {
            float sAi[NPG * 132]; float sBj[NPG * 132]; float sWfT[3 * 132];
            float rv[232]; float sC[HD]; float pD[256]; float pV[256];
            float fp[ASL]; float red[8];
        } hd;
    } sh;

    // ================= Phase 1: GEMM1 partials + AB GEMM =================
    if (bb < G1BLK) {
        int nt = bb % NT, kc = bb / NT;
        int n0 = nt * 64, kb = kc * KCH;
        int klen = min(KCH, SPEC_LEN - kb);   // 55 (41 for last chunk)

        // stage specs -> sA transposed [k][m]: 64 m x 56 k (14*256 = 3584 exact)
#pragma unroll
        for (int p = 0; p < 14; ++p) {
            int e = p * 256 + tid;
            int mm = e / KPAD;
            int k = e - mm * KPAD;
            float v = (k < klen) ? specs[(size_t)mm * SPEC_LEN + kb + k] : 0.0f;
            sh.g1.sA[k * 68 + mm] = v;
        }
        // stage W1 chunk [k][n] as float4 (56*16 = 896 float4s)
#pragma unroll
        for (int p = 0; p < 4; ++p) {
            int e = p * 256 + tid;
            if (e < 896) {
                int kl = e >> 4, nq = (e & 15) * 4;
                float4 v = make_float4(0.f, 0.f, 0.f, 0.f);
                if (kl < klen && (n0 + nq) < S1DIM)
                    v = *(const float4*)&W1[(size_t)(kb + kl) * S1DIM + n0 + nq];
                *(float4*)&sh.g1.sB[kl * 64 + nq] = v;
            }
        }
        __syncthreads();

        int tn = (tid & 15) * 4;
        int tm = (tid >> 4) * 4;
        float acc[4][4] = {};
#pragma unroll 4
        for (int k = 0; k < KPAD; ++k) {
            const float4 a = *(const float4*)&sh.g1.sA[k * 68 + tm];
            const float4 b = *(const float4*)&sh.g1.sB[k * 64 + tn];
            acc[0][0] = fmaf(a.x, b.x, acc[0][0]);
            acc[0][1] = fmaf(a.x, b.y, acc[0][1]);
            acc[0][2] = fmaf(a.x, b.z, acc[0][2]);
            acc[0][3] = fmaf(a.x, b.w, acc[0][3]);
            acc[1][0] = fmaf(a.y, b.x, acc[1][0]);
            acc[1][1] = fmaf(a.y, b.y, acc[1][1]);
            acc[1][2] = fmaf(a.y, b.z, acc[1][2]);
            acc[1][3] = fmaf(a.y, b.w, acc[1][3]);
            acc[2][0] = fmaf(a.z, b.x, acc[2][0]);
            acc[2][1] = fmaf(a.z, b.y, acc[2][1]);
            acc[2][2] = fmaf(a.z, b.z, acc[2][2]);
            acc[2][3] = fmaf(a.z, b.w, acc[2][3]);
            acc[3][0] = fmaf(a.w, b.x, acc[3][0]);
            acc[3][1] = fmaf(a.w, b.y, acc[3][1]);
            acc[3][2] = fmaf(a.w, b.z, acc[3][2]);
            acc[3][3] = fmaf(a.w, b.w, acc[3][3]);
        }

        if (n0 + tn < S1DIM) {   // float4 fully in (900%4==0)
#pragma unroll
            for (int i = 0; i < 4; ++i) {
                float4 o = make_float4(acc[i][0], acc[i][1], acc[i][2], acc[i][3]);
                *(float4*)&P[((size_t)(kc * 64 + tm + i)) * S1DIM + n0 + tn] = o;
            }
        }
    } else {
        // ---- AB = relu(nf) @ Wa2[0:256], 4 rows/block ----
        int ib = (bb - G1BLK) * 4;
        sh.ab.snf[tid]       = fmaxf(nf[(size_t)ib * HD + tid], 0.0f);
        sh.ab.snf[256 + tid] = fmaxf(nf[(size_t)ib * HD + 256 + tid], 0.0f);
        __syncthreads();
        int c = tid;
        const float* __restrict__ wp = (c < HD) ? (Wa2 + c) : (Wa2 + HD * HD + (c - HD));
        float a0 = 0.f, a1 = 0.f, a2 = 0.f, a3 = 0.f;
#pragma unroll 16
        for (int k = 0; k < HD; ++k) {
            float w = wp[(size_t)k * HD];
            a0 = fmaf(sh.ab.snf[k], w, a0);
            a1 = fmaf(sh.ab.snf[HD + k], w, a1);
            a2 = fmaf(sh.ab.snf[2 * HD + k], w, a2);
            a3 = fmaf(sh.ab.snf[3 * HD + k], w, a3);
        }
        AB[(size_t)(ib + 0) * 256 + c] = a0;
        AB[(size_t)(ib + 1) * 256 + c] = a1;
        AB[(size_t)(ib + 2) * 256 + c] = a2;
        AB[(size_t)(ib + 3) * 256 + c] = a3;
    }

    grid_barrier(bar + 0, GRID_BLKS);

    // ================= Phase 2: wide GEMM2 split-K =================
    if (bb < BATCH * 9) {
        int m = bb & 63, q = bb >> 6;         // q in 0..8
        int kb = q * 100;
        if (tid < 100) {
            int k = kb + tid;
            float a = b1[k];
#pragma unroll
            for (int kc = 0; kc < KC; ++kc)
                a += P[((size_t)kc * 64 + m) * S1DIM + k];
            sh.g2.sld[tid] = fmaxf(a, 0.0f);
        }
        __syncthreads();
        if (tid < SCOMP) {
            float a = 0.0f;
#pragma unroll 10
            for (int kl = 0; kl < 100; ++kl)
                a = fmaf(sh.g2.sld[kl], W2[(size_t)(kb + kl) * SCOMP + tid], a);
            Pc[((size_t)q * 64 + m) * SCOMP + tid] = a;
        }
    }

    grid_barrier(bar + 1, GRID_BLKS);

    // ================= Phase 3: per-graph head =================
    if (bb < BATCH) {
        int m = bb;
        // (a) staging — all independent loads
#pragma unroll
        for (int e = tid; e < NPG * 256; e += 256) {
            int i = e >> 8, c = e & 255;
            float v = AB[(size_t)(m * NPG + i) * 256 + c];
            if (c < HD) sh.hd.sAi[i * 132 + c] = v;
            else        sh.hd.sBj[i * 132 + (c - HD)] = v;
        }
        for (int e = tid; e < 3 * HD; e += 256)
            sh.hd.sWfT[(e % 3) * 132 + (e / 3)] = Wf[e];
        if (tid < SCOMP) {
            float a = b2[tid];
#pragma unroll
            for (int q = 0; q < 9; ++q)
                a += Pc[((size_t)q * 64 + m) * SCOMP + tid];
            sh.hd.rv[128 + tid] = fmaxf(a, 0.0f);
        }
        if (tid >= 128) {
            int h = tid - 128;
            float a = 0.0f;
#pragma unroll
            for (int i = 0; i < NPG; ++i) a += nf[(size_t)(m * NPG + i) * HD + h];
            sh.hd.rv[h] = a;
        }
        __syncthreads();

        // (b) D partials (2-way K-split) and value partials (4-way K-split)
        {
            int t = tid & 127, half = tid >> 7;
            float aD = 0.0f;
#pragma unroll 10
            for (int kl = 0; kl < 50; ++kl) {
                int k = half * 50 + kl;
                aD = fmaf(sh.hd.rv[128 + k], Wa2[(size_t)(2 * HD + k) * HD + t], aD);
            }
            sh.hd.pD[tid] = aD;
            int tv = tid & 63, q = tid >> 6;
            float aV = 0.0f;
#pragma unroll 8
            for (int kl = 0; kl < 57; ++kl) {
                int k = q * 57 + kl;
                aV = fmaf(sh.hd.rv[k], Wv1[(size_t)k * 64 + tv], aV);
            }
            sh.hd.pV[tid] = aV;
        }
        __syncthreads();
        if (tid < HD) {
            sh.hd.sC[tid] = sh.hd.pD[tid] + sh.hd.pD[tid + 128] + ba2[tid];
        } else if (tid < 192) {
            int t = tid - 128;
            float a = fmaxf(sh.hd.pV[t] + sh.hd.pV[64 + t] + sh.hd.pV[128 + t] +
                            sh.hd.pV[192 + t] + bv1[t], 0.0f);
            float p = a * Wv2[t];
#pragma unroll
            for (int off = 32; off; off >>= 1) p += __shfl_down(p, off, 64);
            if (tid == 128) vout[m] = p + bv2[0];
        }
        __syncthreads();

        // (c) pair head
        if (tid < ASL) {
            int i = tid / 27;
            int j = (tid / 3) % 9;
            int bo = tid % 3;
            float a = bfb[bo];
            const float* pa = sh.hd.sAi + i * 132;
            const float* pb = sh.hd.sBj + j * 132;
            const float* pw = sh.hd.sWfT + bo * 132;
#pragma unroll 8
            for (int h = 0; h < HD; h += 4) {
                const float4 A = *(const float4*)&pa[h];
                const float4 Bv = *(const float4*)&pb[h];
                const float4 C = *(const float4*)&sh.hd.sC[h];
                const float4 W = *(const float4*)&pw[h];
                a = fmaf(fmaxf(A.x + Bv.x + C.x, 0.f), W.x, a);
                a = fmaf(fmaxf(A.y + Bv.y + C.y, 0.f), W.y, a);
                a = fmaf(fmaxf(A.z + Bv.z + C.z, 0.f), W.z, a);
                a = fmaf(fmaxf(A.w + Bv.w + C.w, 0.f), W.w, a);
            }
            sh.hd.fp[tid] = a;
        }
        __syncthreads();

        // (d) gather + softmax
        float g = -INFINITY;
        if (tid < ASL)
            g = sh.hd.fp[indexmask[(size_t)m * ASL + tid]] + mask[(size_t)m * ASL + tid];
        float mx = g;
#pragma unroll
        for (int off = 32; off; off >>= 1) mx = fmaxf(mx, __shfl_down(mx, off, 64));
        if ((tid & 63) == 0) sh.hd.red[tid >> 6] = mx;
        __syncthreads();
        mx = fmaxf(fmaxf(sh.hd.red[0], sh.hd.red[1]), fmaxf(sh.hd.red[2], sh.hd.red[3]));
        float e = (tid < ASL) ? __expf(g - mx) : 0.0f;
        float sm = e;
#pragma unroll
        for (int off = 32; off; off >>= 1) sm += __shfl_down(sm, off, 64);
        if ((tid & 63) == 0) sh.hd.red[4 + (tid >> 6)] = sm;
        __syncthreads();
        sm = sh.hd.red[4] + sh.hd.red[5] + sh.hd.red[6] + sh.hd.red[7];
        if (tid < ASL) out[(size_t)m * ASL + tid] = e / sm;
    }
}

extern "C" void kernel_launch(void* const* d_in, const int* in_sizes, int n_in,
                              void* d_out, int out_size, void* d_ws, size_t ws_size,
                              hipStream_t stream) {
    (void)in_sizes; (void)n_in; (void)out_size; (void)ws_size;
    const float* nf    = (const float*)d_in[0];
    const float* specs = (const float*)d_in[1];
    const float* mask  = (const float*)d_in[3];
    const int*   idxm  = (const int*)d_in[4];
    const float* W1  = (const float*)d_in[5];
    const float* b1  = (const float*)d_in[6];
    const float* W2  = (const float*)d_in[7];
    const float* b2  = (const float*)d_in[8];
    const float* Wv1 = (const float*)d_in[9];
    const float* bv1 = (const float*)d_in[10];
    const float* Wv2 = (const float*)d_in[11];
    const float* bv2 = (const float*)d_in[12];
    const float* Wa2 = (const float*)d_in[13];
    const float* ba2 = (const float*)d_in[14];
    const float* Wf  = (const float*)d_in[15];
    const float* bfv = (const float*)d_in[16];
    float* out  = (float*)d_out;
    float* vout = out + BATCH * ASL;
    float* ws   = (float*)d_ws;

    float* P  = ws;                            // 33*64*900 = 1,900,800 floats
    float* AB = P + (size_t)KC * 64 * S1DIM;   // 576*256   = 147,456 floats
    float* Pc = AB + (size_t)N_NODES * 256;    // 9*64*100  = 57,600 floats
    unsigned* bar = (unsigned*)(Pc + (size_t)9 * 64 * SCOMP);

    hipMemsetAsync(bar, 0, 2 * sizeof(unsigned), stream);
    kfused<<<dim3(GRID_BLKS), dim3(256), 0, stream>>>(
        specs, W1, nf, Wa2, b1, W2, b2, Wv1, bv1, Wv2, bv2,
        ba2, Wf, bfv, idxm, mask, P, Pc, AB, bar, out, vout);
}

// Round 9
// 126.258 us; speedup vs baseline: 2.5132x; 2.5132x over previous
//
#include <hip/hip_runtime.h>
#include <math.h>

#define BATCH 64
#define NPG 9
#define N_NODES 576
#define HD 128
#define SPEC_LEN 1801
#define S1DIM 900
#define SCOMP 100
#define ASL 243
#define NT 15          // n-tiles of 64 over 900
#define KC 17          // K chunks for GEMM1
#define KCH 106        // 17*106 = 1802 >= 1801
#define KPAD 112       // padded chunk (7*16); k >= klen zeroed in BOTH operands

// ---------- Kernel 1: GEMM1 partials (register-tiled, in-kernel A transpose) + AB GEMM ----------
// blocks 0..254: P[kc][m][n-tile] = specs[m][kchunk] @ W1[kchunk][n-tile]
// blocks 255..398: AB = relu(nf) @ Wa2[0:256]
__global__ __launch_bounds__(256) void k1(const float* __restrict__ specs,
                                          const float* __restrict__ W1,
                                          const float* __restrict__ nf,
                                          const float* __restrict__ Wa2,
                                          float* __restrict__ P,
                                          float* __restrict__ AB) {
    int bb = blockIdx.x, tid = threadIdx.x;
    if (bb < NT * KC) {
        __shared__ __align__(16) float sA[KPAD * 68];   // [k][m], row pad 68
        __shared__ __align__(16) float sB[KPAD * 64];   // [k][n]
        int nt = bb % NT, kc = bb / NT;
        int n0 = nt * 64, kb = kc * KCH;
        int klen = min(KCH, SPEC_LEN - kb);             // 106 (105 for last chunk)

        // stage specs -> sA transposed: ALL 64 m x 112 k  (28 * 256 = 7168)
#pragma unroll
        for (int p = 0; p < 28; ++p) {
            int e = p * 256 + tid;
            int m = e / KPAD;
            int k = e - m * KPAD;
            float v = (k < klen) ? specs[(size_t)m * SPEC_LEN + kb + k] : 0.0f;
            sA[k * 68 + m] = v;
        }
        // stage W1 chunk (float4; zero for k >= klen or n out of range)
#pragma unroll
        for (int p = 0; p < 7; ++p) {
            int e = p * 256 + tid;
            int kl = e >> 4, nq = (e & 15) * 4;
            float4 v = make_float4(0.f, 0.f, 0.f, 0.f);
            if (kl < klen && (n0 + nq) < S1DIM)
                v = *(const float4*)&W1[(size_t)(kb + kl) * S1DIM + n0 + nq];
            *(float4*)&sB[kl * 64 + nq] = v;
        }
        __syncthreads();

        int tn = (tid & 15) * 4;
        int tm = (tid >> 4) * 4;
        float acc[4][4] = {};
#pragma unroll 4
        for (int k = 0; k < KPAD; ++k) {
            const float4 a = *(const float4*)&sA[k * 68 + tm];
            const float4 b = *(const float4*)&sB[k * 64 + tn];
            acc[0][0] = fmaf(a.x, b.x, acc[0][0]);
            acc[0][1] = fmaf(a.x, b.y, acc[0][1]);
            acc[0][2] = fmaf(a.x, b.z, acc[0][2]);
            acc[0][3] = fmaf(a.x, b.w, acc[0][3]);
            acc[1][0] = fmaf(a.y, b.x, acc[1][0]);
            acc[1][1] = fmaf(a.y, b.y, acc[1][1]);
            acc[1][2] = fmaf(a.y, b.z, acc[1][2]);
            acc[1][3] = fmaf(a.y, b.w, acc[1][3]);
            acc[2][0] = fmaf(a.z, b.x, acc[2][0]);
            acc[2][1] = fmaf(a.z, b.y, acc[2][1]);
            acc[2][2] = fmaf(a.z, b.z, acc[2][2]);
            acc[2][3] = fmaf(a.z, b.w, acc[2][3]);
            acc[3][0] = fmaf(a.w, b.x, acc[3][0]);
            acc[3][1] = fmaf(a.w, b.y, acc[3][1]);
            acc[3][2] = fmaf(a.w, b.z, acc[3][2]);
            acc[3][3] = fmaf(a.w, b.w, acc[3][3]);
        }

        if (n0 + tn < S1DIM) {   // float4 fully in (900%4==0)
#pragma unroll
            for (int i = 0; i < 4; ++i) {
                float4 o = make_float4(acc[i][0], acc[i][1], acc[i][2], acc[i][3]);
                *(float4*)&P[((size_t)(kc * 64 + tm + i)) * S1DIM + n0 + tn] = o;
            }
        }
    } else {
        // ---- AB = relu(nf) @ Wa2[0:256], 4 rows/block ----
        __shared__ float snf[4 * HD];
        int ib = (bb - NT * KC) * 4;
        snf[tid]       = fmaxf(nf[(size_t)ib * HD + tid], 0.0f);
        snf[256 + tid] = fmaxf(nf[(size_t)ib * HD + 256 + tid], 0.0f);
        __syncthreads();
        int c = tid;
        const float* __restrict__ wp = (c < HD) ? (Wa2 + c) : (Wa2 + HD * HD + (c - HD));
        float a0 = 0.f, a1 = 0.f, a2 = 0.f, a3 = 0.f;
#pragma unroll 16
        for (int k = 0; k < HD; ++k) {
            float w = wp[(size_t)k * HD];
            a0 = fmaf(snf[k], w, a0);
            a1 = fmaf(snf[HD + k], w, a1);
            a2 = fmaf(snf[2 * HD + k], w, a2);
            a3 = fmaf(snf[3 * HD + k], w, a3);
        }
        AB[(size_t)(ib + 0) * 256 + c] = a0;
        AB[(size_t)(ib + 1) * 256 + c] = a1;
        AB[(size_t)(ib + 2) * 256 + c] = a2;
        AB[(size_t)(ib + 3) * 256 + c] = a3;
    }
}

// ---------- Kernel 2: wide GEMM2 split-K: Pc[q][m][c] = relu(s1_chunk) @ W2_chunk ----------
// grid (64, 9), 128 threads. Each block builds its own disjoint s1 chunk from P.
__global__ __launch_bounds__(128) void k2(const float* __restrict__ P,
                                          const float* __restrict__ b1,
                                          const float* __restrict__ W2,
                                          float* __restrict__ Pc) {
    __shared__ float sld[100];
    int m = blockIdx.x, kc9 = blockIdx.y, tid = threadIdx.x;
    int kb = kc9 * 100;
    if (tid < 100) {
        int k = kb + tid;
        float a = b1[k];
#pragma unroll
        for (int kc = 0; kc < KC; ++kc)
            a += P[((size_t)kc * 64 + m) * S1DIM + k];
        sld[tid] = fmaxf(a, 0.0f);
    }
    __syncthreads();
    if (tid < SCOMP) {
        float a = 0.0f;
#pragma unroll 10
        for (int kl = 0; kl < 100; ++kl)
            a = fmaf(sld[kl], W2[(size_t)(kb + kl) * SCOMP + tid], a);
        Pc[((size_t)kc9 * 64 + m) * SCOMP + tid] = a;
    }
}

// ---------- Kernel 3: per-graph head: srow, D, value, pair features, gather, softmax ----------
__global__ __launch_bounds__(256) void k3(const float* __restrict__ Pc,
                                          const float* __restrict__ b2,
                                          const float* __restrict__ Wa2,
                                          const float* __restrict__ nf,
                                          const float* __restrict__ Wv1,
                                          const float* __restrict__ bv1,
                                          const float* __restrict__ Wv2,
                                          const float* __restrict__ bv2,
                                          const float* __restrict__ ba2,
                                          const float* __restrict__ Wf,
                                          const float* __restrict__ bfb,
                                          const int* __restrict__ indexmask,
                                          const float* __restrict__ mask,
                                          const float* __restrict__ AB,
                                          float* __restrict__ out,
                                          float* __restrict__ vout) {
    int m = blockIdx.x, tid = threadIdx.x;
    __shared__ __align__(16) float sAi[NPG * 132];
    __shared__ __align__(16) float sBj[NPG * 132];
    __shared__ __align__(16) float sWfT[3 * 132];
    __shared__ __align__(16) float rv[232];      // rv[0:128]=readout, rv[128:228]=srow
    __shared__ __align__(16) float sC[HD];
    __shared__ float pD[256];
    __shared__ float pV[256];
    __shared__ float fp[ASL];
    __shared__ float red[8];

    // (a) staging — all independent loads; AB via float4 (576 float4s)
#pragma unroll
    for (int p = 0; p < 3; ++p) {
        int e4 = p * 256 + tid;
        if (e4 < NPG * 64) {
            int i = e4 >> 6, c = (e4 & 63) * 4;
            float4 v = *(const float4*)&AB[(size_t)(m * NPG + i) * 256 + c];
            if (c < HD) *(float4*)&sAi[i * 132 + c] = v;
            else        *(float4*)&sBj[i * 132 + (c - HD)] = v;
        }
    }
    for (int e = tid; e < 3 * HD; e += 256)
        sWfT[(e % 3) * 132 + (e / 3)] = Wf[e];
    if (tid < SCOMP) {
        float a = b2[tid];
#pragma unroll
        for (int q = 0; q < 9; ++q)
            a += Pc[((size_t)q * 64 + m) * SCOMP + tid];
        rv[128 + tid] = fmaxf(a, 0.0f);
    }
    if (tid >= 128) {
        int h = tid - 128;
        float a = 0.0f;
#pragma unroll
        for (int i = 0; i < NPG; ++i) a += nf[(size_t)(m * NPG + i) * HD + h];
        rv[h] = a;
    }
    __syncthreads();

    // (b) D partials (2-way K-split over 256 thr) and value partials (4-way K-split)
    {
        int t = tid & 127, half = tid >> 7;
        float aD = 0.0f;
#pragma unroll 10
        for (int kl = 0; kl < 50; ++kl) {
            int k = half * 50 + kl;
            aD = fmaf(rv[128 + k], Wa2[(size_t)(2 * HD + k) * HD + t], aD);
        }
        pD[tid] = aD;
        int tv = tid & 63, q = tid >> 6;
        float aV = 0.0f;
#pragma unroll 8
        for (int kl = 0; kl < 57; ++kl) {
            int k = q * 57 + kl;
            aV = fmaf(rv[k], Wv1[(size_t)k * 64 + tv], aV);
        }
        pV[tid] = aV;
    }
    __syncthreads();
    if (tid < HD) {
        sC[tid] = pD[tid] + pD[tid + 128] + ba2[tid];
    } else if (tid < 192) {
        int t = tid - 128;
        float a = fmaxf(pV[t] + pV[64 + t] + pV[128 + t] + pV[192 + t] + bv1[t], 0.0f);
        float p = a * Wv2[t];
#pragma unroll
        for (int off = 32; off; off >>= 1) p += __shfl_down(p, off, 64);
        if (tid == 128) vout[m] = p + bv2[0];
    }
    __syncthreads();

    // (c) pair head: fp[i,j,bond]
    if (tid < ASL) {
        int i = tid / 27;
        int j = (tid / 3) % 9;
        int bo = tid % 3;
        float a = bfb[bo];
        const float* pa = sAi + i * 132;
        const float* pb = sBj + j * 132;
        const float* pw = sWfT + bo * 132;
#pragma unroll 8
        for (int h = 0; h < HD; h += 4) {
            const float4 A = *(const float4*)&pa[h];
            const float4 Bv = *(const float4*)&pb[h];
            const float4 C = *(const float4*)&sC[h];
            const float4 W = *(const float4*)&pw[h];
            a = fmaf(fmaxf(A.x + Bv.x + C.x, 0.f), W.x, a);
            a = fmaf(fmaxf(A.y + Bv.y + C.y, 0.f), W.y, a);
            a = fmaf(fmaxf(A.z + Bv.z + C.z, 0.f), W.z, a);
            a = fmaf(fmaxf(A.w + Bv.w + C.w, 0.f), W.w, a);
        }
        fp[tid] = a;
    }
    __syncthreads();

    // (d) gather + softmax
    float g = -INFINITY;
    if (tid < ASL) g = fp[indexmask[(size_t)m * ASL + tid]] + mask[(size_t)m * ASL + tid];
    float mx = g;
#pragma unroll
    for (int off = 32; off; off >>= 1) mx = fmaxf(mx, __shfl_down(mx, off, 64));
    if ((tid & 63) == 0) red[tid >> 6] = mx;
    __syncthreads();
    mx = fmaxf(fmaxf(red[0], red[1]), fmaxf(red[2], red[3]));
    float e = (tid < ASL) ? __expf(g - mx) : 0.0f;
    float sm = e;
#pragma unroll
    for (int off = 32; off; off >>= 1) sm += __shfl_down(sm, off, 64);
    if ((tid & 63) == 0) red[4 + (tid >> 6)] = sm;
    __syncthreads();
    sm = red[4] + red[5] + red[6] + red[7];
    if (tid < ASL) out[(size_t)m * ASL + tid] = e / sm;
}

extern "C" void kernel_launch(void* const* d_in, const int* in_sizes, int n_in,
                              void* d_out, int out_size, void* d_ws, size_t ws_size,
                              hipStream_t stream) {
    (void)in_sizes; (void)n_in; (void)out_size; (void)ws_size;
    const float* nf    = (const float*)d_in[0];
    const float* specs = (const float*)d_in[1];
    const float* mask  = (const float*)d_in[3];
    const int*   idxm  = (const int*)d_in[4];
    const float* W1  = (const float*)d_in[5];
    const float* b1  = (const float*)d_in[6];
    const float* W2  = (const float*)d_in[7];
    const float* b2  = (const float*)d_in[8];
    const float* Wv1 = (const float*)d_in[9];
    const float* bv1 = (const float*)d_in[10];
    const float* Wv2 = (const float*)d_in[11];
    const float* bv2 = (const float*)d_in[12];
    const float* Wa2 = (const float*)d_in[13];
    const float* ba2 = (const float*)d_in[14];
    const float* Wf  = (const float*)d_in[15];
    const float* bfv = (const float*)d_in[16];
    float* out = (float*)d_out;
    float* ws  = (float*)d_ws;

    float* P  = ws;                            // 17*64*900 = 979200 floats
    float* AB = P + (size_t)KC * 64 * S1DIM;   // 576*256   = 147456 floats
    float* Pc = AB + (size_t)N_NODES * 256;    // 9*64*100  = 57600 floats

    k1<<<dim3(NT * KC + N_NODES / 4), dim3(256), 0, stream>>>(specs, W1, nf, Wa2, P, AB);
    k2<<<dim3(BATCH, 9), dim3(128), 0, stream>>>(P, b1, W2, Pc);
    k3<<<dim3(BATCH), dim3(256), 0, stream>>>(Pc, b2, Wa2, nf,
                                              Wv1, bv1, Wv2, bv2, ba2, Wf, bfv,
                                              idxm, mask, AB, out, out + BATCH * ASL);
}